// Round 1
// baseline (901.983 us; speedup 1.0000x reference)
//
#include <hip/hip_runtime.h>
#include <hip/hip_fp16.h>

#define S_LEN 512
#define BATCH 32
#define CHUNK 16

typedef _Float16 hv2  __attribute__((ext_vector_type(2)));
typedef _Float16 half8 __attribute__((ext_vector_type(8)));
typedef float    f32x4 __attribute__((ext_vector_type(4)));

__device__ __forceinline__ float dot2f(hv2 a, hv2 b, float c) {
#if __has_builtin(__builtin_amdgcn_fdot2)
    return __builtin_amdgcn_fdot2(a, b, c, false);
#else
    return c + (float)a.x * (float)b.x + (float)a.y * (float)b.y;
#endif
}

__device__ __forceinline__ float fast_tanh(float x) {
    float e = __expf(2.f * x);
    return 1.f - 2.f / (e + 1.f);
}

// Step barrier that does NOT drain vmcnt: LDS-only visibility.
__device__ __forceinline__ void lds_barrier() {
    __asm__ volatile("s_waitcnt lgkmcnt(0)\n\ts_barrier" ::: "memory");
}
__device__ __forceinline__ void vm_drain() {
    __asm__ volatile("s_waitcnt vmcnt(0)" ::: "memory");
}

// ---------------------------------------------------------------------------
// Prep: convert to padded f16 (relu fused for emb). Zeroes flags.
// ---------------------------------------------------------------------------
#define E8   1280000   // 32000*320/8
#define W18  64000     // 320*1600/8
#define W28  12800     // 320*320/8
#define FF8  5120      // 128*320/8
#define PREP_TOTAL8 (E8 + W18 + W28 + FF8 + FF8)

__global__ __launch_bounds__(256) void k_prep(
    const float* __restrict__ emb,  const float* __restrict__ Wih1,
    const float* __restrict__ Wih2, const float* __restrict__ fc1w,
    const float* __restrict__ fc2w,
    _Float16* __restrict__ embf, _Float16* __restrict__ Wf1,
    _Float16* __restrict__ Wf2,  _Float16* __restrict__ F1,
    _Float16* __restrict__ F2,   unsigned int* __restrict__ flags)
{
    int gid = blockIdx.x * 256 + threadIdx.x;
    if (gid < 64) flags[gid] = 0u;
    if (gid >= PREP_TOTAL8) return;

    half8 v;
    _Float16* dst;

    if (gid < E8) {
        int row = gid / 40, c8 = (gid - row * 40) * 8;
        #pragma unroll
        for (int j = 0; j < 8; ++j) {
            int c = c8 + j;
            float f = (c < 300) ? emb[(size_t)row * 300 + c] : 0.f;
            v[j] = (_Float16)(f > 0.f ? f : 0.f);
        }
        dst = embf + (size_t)gid * 8;
    } else if (gid < E8 + W18) {
        int i = gid - E8;
        int row = i / 200, c8 = (i - row * 200) * 8;
        #pragma unroll
        for (int j = 0; j < 8; ++j) {
            int c = c8 + j, w = c / 320, cc = c - w * 320;
            float f = (row < 300 && cc < 300) ? Wih1[(size_t)row * 1500 + w * 300 + cc] : 0.f;
            v[j] = (_Float16)f;
        }
        dst = Wf1 + (size_t)i * 8;
    } else if (gid < E8 + W18 + W28) {
        int i = gid - E8 - W18;
        int row = i / 40, c8 = (i - row * 40) * 8;
        #pragma unroll
        for (int j = 0; j < 8; ++j) {
            int c = c8 + j;
            float f = (row < 300 && c < 300) ? Wih2[(size_t)row * 300 + c] : 0.f;
            v[j] = (_Float16)f;
        }
        dst = Wf2 + (size_t)i * 8;
    } else if (gid < E8 + W18 + W28 + FF8) {
        int i = gid - E8 - W18 - W28;
        int row = i / 40, c8 = (i - row * 40) * 8;
        #pragma unroll
        for (int j = 0; j < 8; ++j) {
            int c = c8 + j;
            v[j] = (_Float16)((c < 300) ? fc1w[(size_t)row * 300 + c] : 0.f);
        }
        dst = F1 + (size_t)i * 8;
    } else {
        int i = gid - E8 - W18 - W28 - FF8;
        int row = i / 40, c8 = (i - row * 40) * 8;
        #pragma unroll
        for (int j = 0; j < 8; ++j) {
            int c = c8 + j;
            v[j] = (_Float16)((c < 300) ? fc2w[(size_t)row * 300 + c] : 0.f);
        }
        dst = F2 + (size_t)i * 8;
    }
    *(half8*)dst = v;
}

// ---------------------------------------------------------------------------
// GEMM1 (MFMA, fused embedding gather). grid (128,2), block 256.
// ---------------------------------------------------------------------------
__global__ __launch_bounds__(256) void k_gemm1_mfma(
    const int* __restrict__ x, const _Float16* __restrict__ embf,
    const _Float16* __restrict__ Wf1, const float* __restrict__ b1,
    const float* __restrict__ b2, float* __restrict__ U)
{
    const int wid  = threadIdx.x >> 6;
    const int lane = threadIdx.x & 63;
    const int m    = lane & 15;
    const int q    = lane >> 4;
    const int r0   = blockIdx.x * 128 + wid * 32;
    const int n0   = blockIdx.y * 160;

    f32x4 acc[2][10];
    #pragma unroll
    for (int i = 0; i < 2; ++i)
        #pragma unroll
        for (int j = 0; j < 10; ++j)
            acc[i][j] = (f32x4){0.f, 0.f, 0.f, 0.f};

    const int rA = r0 + m, rB = r0 + 16 + m;
    const int xbA = ((rA & 31) * S_LEN + (rA >> 5)) * 5;
    const int xbB = ((rB & 31) * S_LEN + (rB >> 5)) * 5;

    for (int w = 0; w < 5; ++w) {
        const int idxA = x[xbA + w];
        const int idxB = x[xbB + w];
        const _Float16* ea = embf + (size_t)idxA * 320;
        const _Float16* eb = embf + (size_t)idxB * 320;
        const _Float16* wb = Wf1 + (size_t)w * 320;
        #pragma unroll
        for (int c = 0; c < 10; ++c) {
            const int k = c * 32 + q * 8;
            half8 a0 = *(const half8*)(ea + k);
            half8 a1 = *(const half8*)(eb + k);
            #pragma unroll
            for (int nt = 0; nt < 10; ++nt) {
                half8 bf = *(const half8*)(wb + (size_t)(n0 + nt * 16 + m) * 1600 + k);
                acc[0][nt] = __builtin_amdgcn_mfma_f32_16x16x32_f16(a0, bf, acc[0][nt], 0, 0, 0);
                acc[1][nt] = __builtin_amdgcn_mfma_f32_16x16x32_f16(a1, bf, acc[1][nt], 0, 0, 0);
            }
        }
    }

    #pragma unroll
    for (int nt = 0; nt < 10; ++nt) {
        const int n = n0 + nt * 16 + m;
        if (n >= 300) continue;
        const float bias = b1[n] + b2[n];
        #pragma unroll
        for (int mt = 0; mt < 2; ++mt) {
            const int rbase = r0 + mt * 16 + q * 4;
            #pragma unroll
            for (int reg = 0; reg < 4; ++reg)
                U[(size_t)(rbase + reg) * 300 + n] = acc[mt][nt][reg] + bias;
        }
    }
}

// ---------------------------------------------------------------------------
// FC (MFMA): per-wave 32x128. grid (128, 2): y = layer.
// ---------------------------------------------------------------------------
__global__ __launch_bounds__(256) void k_fc_mfma(
    const _Float16* __restrict__ H1, const _Float16* __restrict__ H2,
    const _Float16* __restrict__ F1, const _Float16* __restrict__ F2,
    const float* __restrict__ fb1, const float* __restrict__ fb2,
    float* __restrict__ out1, float* __restrict__ out2)
{
    const int layer = blockIdx.y;
    const _Float16* H = layer ? H2 : H1;
    const _Float16* F = layer ? F2 : F1;
    const float* bias = layer ? fb2 : fb1;
    float* out        = layer ? out2 : out1;

    const int wid  = threadIdx.x >> 6;
    const int lane = threadIdx.x & 63;
    const int m    = lane & 15;
    const int q    = lane >> 4;
    const int r0   = blockIdx.x * 128 + wid * 32;

    f32x4 acc[2][8];
    #pragma unroll
    for (int i = 0; i < 2; ++i)
        #pragma unroll
        for (int j = 0; j < 8; ++j)
            acc[i][j] = (f32x4){0.f, 0.f, 0.f, 0.f};

    const _Float16* ha = H + (size_t)(r0 + m) * 320;
    const _Float16* hb = H + (size_t)(r0 + 16 + m) * 320;

    #pragma unroll
    for (int c = 0; c < 10; ++c) {
        const int k = c * 32 + q * 8;
        half8 a0 = *(const half8*)(ha + k);
        half8 a1 = *(const half8*)(hb + k);
        #pragma unroll
        for (int nt = 0; nt < 8; ++nt) {
            half8 bf = *(const half8*)(F + (size_t)(nt * 16 + m) * 320 + k);
            acc[0][nt] = __builtin_amdgcn_mfma_f32_16x16x32_f16(a0, bf, acc[0][nt], 0, 0, 0);
            acc[1][nt] = __builtin_amdgcn_mfma_f32_16x16x32_f16(a1, bf, acc[1][nt], 0, 0, 0);
        }
    }

    #pragma unroll
    for (int nt = 0; nt < 8; ++nt) {
        const int n = nt * 16 + m;
        const float bv = bias[n];
        #pragma unroll
        for (int mt = 0; mt < 2; ++mt) {
            #pragma unroll
            for (int reg = 0; reg < 4; ++reg) {
                const int r = r0 + mt * 16 + q * 4 + reg;
                const int oidx = ((r & 31) * S_LEN + (r >> 5)) * 128 + n;
                out[oidx] = acc[mt][nt][reg] + bv;
            }
        }
    }
}

// ---------------------------------------------------------------------------
// Fused recurrence. 64 blocks x 512 threads (8 waves).
// Wave w owns h-columns [40w, 40w+40). Lane l holds Whh rows {l+64i, i<5}
// for those columns (5x20 hv2 in VGPRs).
// Step = phase A (v_readlane h-broadcast from lanes 0..19 -> 100 dot2 ->
// 5 partial writes, double-buffered by step parity) -> ONE lds_barrier ->
// phase B (lanes 0..39: 8 conflict-free partial reads + U + tanh; pack to
// hv2 in lanes 0..19 via 2 ds_bpermute). h never round-trips LDS in the
// critical chain; it lives in registers across steps AND chunks.
// Chunk/flag pipeline unchanged: producer (blocks 0..31) bulk-stores H1
// chunks + releases flags; consumer (blocks 32..63) stages h1 (XOR-swizzled
// to kill the 16-way MFMA bank conflict), computes U2 via MFMA, runs steps.
// Dynamic LDS layout (byte offsets):
//   partials float[2][8][320]  @ 0      (20480)  K-group partials, dbuf
//   hc       f16  [16][320]    @ 20480  (10240)  h chunk ring (for stores)
//   uc       f32  [16][304]    @ 30720  (19456)  U1-chunk / U2-chunk
//   h1s      f16  [16][320]sw  @ 50176  (10240)  consumer staged h1 (swizzled)
// ---------------------------------------------------------------------------
#define LDS_BYTES 60416

__device__ __forceinline__ void load_u_regs(float* up, const float* __restrict__ U1,
                                            int b, int t0) {
    #pragma unroll
    for (int j = 0; j < 10; ++j) {
        int e = threadIdx.x + 512 * j;
        int row = e / 300, col = e - row * 300;
        up[j] = (e < 4800) ? U1[((size_t)((t0 + row) * BATCH + b)) * 300 + col] : 0.f;
    }
}

__global__ __launch_bounds__(512) void k_rec_fused(
    const float* __restrict__ U1, const float* __restrict__ Whh1,
    const _Float16* __restrict__ Wf2, const float* __restrict__ Whh2,
    const float* __restrict__ bih2, const float* __restrict__ bhh2,
    _Float16* __restrict__ H1f, _Float16* __restrict__ H2f,
    unsigned int* __restrict__ flags)
{
    extern __shared__ char smem[];
    float    (*partials)[8][320] = (float(*)[8][320])smem;        // 20480
    _Float16 (*hc)[320]  = (_Float16(*)[320])(smem + 20480);      // 10240
    float    (*uc)[304]  = (float(*)[304])(smem + 30720);         // 19456
    char*     h1sb       = smem + 50176;                          // 10240 swizzled

    const int tid  = threadIdx.x;
    const int wv   = tid >> 6;          // wave id = K-column group
    const int lane = tid & 63;
    const int r    = wv * 40 + lane;    // phase-B output row (lane < 40)
    const bool prod = blockIdx.x < 32;
    const int b    = prod ? (int)blockIdx.x : (int)blockIdx.x - 32;

    // zero h ring once (pad cols 300..319 must stay 0 forever)
    for (int i = tid; i < CHUNK * 320; i += 512)
        ((_Float16*)hc)[i] = (_Float16)0.f;

    // ---- recurrent weights into registers: rows {lane+64i}, cols [40wv,+40) ----
    const float* Whh = prod ? Whh1 : Whh2;
    hv2 wreg[5][20];
    #pragma unroll
    for (int i = 0; i < 5; ++i) {
        const int row = lane + 64 * i;
        const float* wrow = Whh + (size_t)row * 300 + 40 * wv;
        #pragma unroll
        for (int j = 0; j < 20; ++j) {
            const int c0 = 40 * wv + 2 * j;
            hv2 p;
            p.x = (row < 300 && c0     < 300) ? (_Float16)wrow[2 * j]     : (_Float16)0.f;
            p.y = (row < 300 && c0 + 1 < 300) ? (_Float16)wrow[2 * j + 1] : (_Float16)0.f;
            wreg[i][j] = p;
        }
    }

    const float biasc = (!prod && lane < 40 && r < 300) ? (bih2[r] + bhh2[r]) : 0.f;

    // h_{t-1} packed f16x2: lanes 0..19 hold cols {40wv+2j, 40wv+2j+1}.
    unsigned hpk = 0u;   // h_{-1} = 0

    auto do_step = [&](int s) {
        const int par = s & 1;
        // ---- phase A: partial dots from register-resident h broadcast ----
        float a0 = 0.f, a1 = 0.f, a2 = 0.f, a3 = 0.f, a4 = 0.f;
        #pragma unroll
        for (int j = 0; j < 20; ++j) {
            const unsigned hj = __builtin_amdgcn_readlane(hpk, j);
            const hv2 hvv = __builtin_bit_cast(hv2, hj);
            a0 = dot2f(wreg[0][j], hvv, a0);
            a1 = dot2f(wreg[1][j], hvv, a1);
            a2 = dot2f(wreg[2][j], hvv, a2);
            a3 = dot2f(wreg[3][j], hvv, a3);
            a4 = dot2f(wreg[4][j], hvv, a4);
        }
        partials[par][wv][lane      ] = a0;
        partials[par][wv][lane +  64] = a1;
        partials[par][wv][lane + 128] = a2;
        partials[par][wv][lane + 192] = a3;
        partials[par][wv][lane + 256] = a4;
        const bool act = (lane < 40) && (r < 300);
        float uval = act ? (uc[s][r] + biasc) : 0.f;
        lds_barrier();
        // ---- phase B: own-slice reduce + tanh; repack h into lanes 0..19 ----
        float v = 0.f;
        if (act) {
            float s01 = partials[par][0][r] + partials[par][1][r];
            float s23 = partials[par][2][r] + partials[par][3][r];
            float s45 = partials[par][4][r] + partials[par][5][r];
            float s67 = partials[par][6][r] + partials[par][7][r];
            v = fast_tanh(uval + ((s01 + s23) + (s45 + s67)));
            hc[s][r] = (_Float16)v;         // for bulk store only (off-chain)
        }
        const float pa = __shfl(v, 2 * lane);
        const float pb = __shfl(v, 2 * lane + 1);
        hv2 hp2; hp2.x = (_Float16)pa; hp2.y = (_Float16)pb;
        hpk = __builtin_bit_cast(unsigned, hp2);
        // no second barrier: next step writes the other partials buffer
    };

    if (prod) {
        // ========================= producer: layer 1 =========================
        float upref[10];
        load_u_regs(upref, U1, b, 0);

        for (int c = 0; c < 32; ++c) {
            const int t0 = c * CHUNK;
            if (c > 0) {
                const int tb = t0 - CHUNK;
                for (int i = tid; i < CHUNK * 40; i += 512) {
                    int row = i / 40, c8 = i - row * 40;
                    half8 vv = *(const half8*)&hc[row][c8 * 8];
                    *(half8*)&H1f[((size_t)((tb + row) * BATCH + b)) * 320 + c8 * 8] = vv;
                }
            }
            // stage this chunk's U into LDS from prefetch regs
            #pragma unroll
            for (int j = 0; j < 10; ++j) {
                int e = tid + 512 * j;
                if (e < 4800) {
                    int row = e / 300, col = e - row * 300;
                    uc[row][col] = upref[j];
                }
            }
            if (c > 0) {
                vm_drain();   // H1 stores complete before release
                if (tid == 0)
                    __hip_atomic_store(&flags[b], (unsigned)t0,
                                       __ATOMIC_RELEASE, __HIP_MEMORY_SCOPE_AGENT);
            }
            if (c + 1 < 32)
                load_u_regs(upref, U1, b, t0 + CHUNK);   // in flight across steps
            lds_barrier();

            for (int s = 0; s < CHUNK; ++s) do_step(s);
            lds_barrier();   // hc/uc WAR vs next chunk's store/staging
        }
        // final chunk store + flag
        {
            const int tb = S_LEN - CHUNK;
            for (int i = tid; i < CHUNK * 40; i += 512) {
                int row = i / 40, c8 = i - row * 40;
                half8 vv = *(const half8*)&hc[row][c8 * 8];
                *(half8*)&H1f[((size_t)((tb + row) * BATCH + b)) * 320 + c8 * 8] = vv;
            }
            vm_drain();
            if (tid == 0)
                __hip_atomic_store(&flags[b], (unsigned)S_LEN,
                                   __ATOMIC_RELEASE, __HIP_MEMORY_SCOPE_AGENT);
        }
    } else {
        // ========================= consumer: layer 2 =========================
        for (int c = 0; c < 32; ++c) {
            const int t0 = c * CHUNK;
            if (c > 0) {
                const int tb = t0 - CHUNK;
                for (int i = tid; i < CHUNK * 40; i += 512) {
                    int row = i / 40, c8 = i - row * 40;
                    half8 vv = *(const half8*)&hc[row][c8 * 8];
                    *(half8*)&H2f[((size_t)((tb + row) * BATCH + b)) * 320 + c8 * 8] = vv;
                }
            }
            if (tid == 0) {
                while (__hip_atomic_load(&flags[b], __ATOMIC_ACQUIRE,
                                         __HIP_MEMORY_SCOPE_AGENT) < (unsigned)(t0 + CHUNK))
                    __builtin_amdgcn_s_sleep(2);
            }
            __syncthreads();   // orders after poll; drains H2 stores (once/chunk)

            // stage this chunk's h1 into LDS, XOR-swizzled (kills 16-way
            // bank conflict on the MFMA A-reads below)
            for (int i = tid; i < CHUNK * 40; i += 512) {
                int row = i / 40, c8 = i - row * 40;
                half8 vv = *(const half8*)&H1f[((size_t)((t0 + row) * BATCH + b)) * 320 + c8 * 8];
                *(half8*)(h1sb + row * 640 + ((c8 * 16) ^ ((row & 7) << 4))) = vv;
            }
            lds_barrier();

            // U2-chunk = h1s @ Wf2^T via MFMA (M=16 steps, N=304, K=320)
            {
                const int lm = lane & 15, lq = lane >> 4;
                for (int nt = wv; nt < 19; nt += 8) {
                    f32x4 acc = (f32x4){0.f, 0.f, 0.f, 0.f};
                    const int n = nt * 16 + lm;
                    const _Float16* wrow2 = Wf2 + (size_t)n * 320;
                    #pragma unroll
                    for (int k0 = 0; k0 < 320; k0 += 32) {
                        half8 av = *(const half8*)(h1sb + lm * 640 +
                                    (((k0 + lq * 8) * 2) ^ ((lm & 7) << 4)));
                        half8 bf = *(const half8*)&wrow2[k0 + lq * 8];
                        acc = __builtin_amdgcn_mfma_f32_16x16x32_f16(av, bf, acc, 0, 0, 0);
                    }
                    #pragma unroll
                    for (int reg = 0; reg < 4; ++reg)
                        uc[lq * 4 + reg][n] = acc[reg];
                }
            }
            lds_barrier();

            for (int s = 0; s < CHUNK; ++s) do_step(s);
            lds_barrier();
        }
        // final H2 chunk store
        {
            const int tb = S_LEN - CHUNK;
            for (int i = tid; i < CHUNK * 40; i += 512) {
                int row = i / 40, c8 = i - row * 40;
                half8 vv = *(const half8*)&hc[row][c8 * 8];
                *(half8*)&H2f[((size_t)((tb + row) * BATCH + b)) * 320 + c8 * 8] = vv;
            }
        }
    }
}

extern "C" void kernel_launch(void* const* d_in, const int* in_sizes, int n_in,
                              void* d_out, int out_size, void* d_ws, size_t ws_size,
                              hipStream_t stream) {
    const int*   x     = (const int*)d_in[0];
    const float* emb   = (const float*)d_in[1];
    const float* Wih1  = (const float*)d_in[2];
    const float* Whh1  = (const float*)d_in[3];
    const float* bih1  = (const float*)d_in[4];
    const float* bhh1  = (const float*)d_in[5];
    const float* Wih2  = (const float*)d_in[6];
    const float* Whh2  = (const float*)d_in[7];
    const float* bih2  = (const float*)d_in[8];
    const float* bhh2  = (const float*)d_in[9];
    const float* fc1w  = (const float*)d_in[10];
    const float* fc1b  = (const float*)d_in[11];
    const float* fc2w  = (const float*)d_in[12];
    const float* fc2b  = (const float*)d_in[13];

    float* out1 = (float*)d_out;
    float* out2 = out1 + (size_t)16384 * 128;

    char* w = (char*)d_ws;
    float*        U1    = (float*)w;                     // 19,660,800
    _Float16*     H1    = (_Float16*)(w + 19660800);     // 10,485,760
    _Float16*     Wf1   = (_Float16*)(w + 30146560);     //  1,024,000
    _Float16*     Wf2   = (_Float16*)(w + 31170560);     //    204,800
    _Float16*     F1    = (_Float16*)(w + 31375360);     //     81,920
    _Float16*     F2    = (_Float16*)(w + 31457280);     //     81,920
    unsigned int* flags = (unsigned int*)(w + 31539200); //        256
    _Float16*     EMBF  = (_Float16*)(w + 31539456);     // 20,480,000
    _Float16*     H2    = EMBF;  // reuse: gemm1 done with EMBF before rec writes H2

    const int prep_blocks = (PREP_TOTAL8 + 255) / 256;
    k_prep<<<prep_blocks, 256, 0, stream>>>(emb, Wih1, Wih2, fc1w, fc2w,
                                            EMBF, Wf1, Wf2, F1, F2, flags);

    dim3 g(128, 2);
    k_gemm1_mfma<<<g, 256, 0, stream>>>(x, EMBF, Wf1, bih1, bhh1, U1);
    k_rec_fused<<<64, 512, LDS_BYTES, stream>>>(U1, Whh1, Wf2, Whh2, bih2, bhh2,
                                                H1, H2, flags);
    k_fc_mfma<<<g, 256, 0, stream>>>(H1, H2, F1, F2, fc1b, fc2b, out1, out2);
}